// Round 15
// baseline (555.249 us; speedup 1.0000x reference)
//
#include <hip/hip_runtime.h>
#include <hip/hip_bf16.h>
#include <stdint.h>

typedef __attribute__((ext_vector_type(8))) short bf16x8;
typedef __attribute__((ext_vector_type(4))) float f32x4;

#define B_   2
#define SQ_  2048
#define H_   4096
#define NH_  32
#define NG_  2
#define HN_  128
#define QKVO 4608

__device__ __forceinline__ unsigned short f2b(float f) {
    union { float f; uint32_t u; } v; v.f = f;
    uint32_t u = v.u;
    u += 0x7FFFu + ((u >> 16) & 1u);   // round-to-nearest-even
    return (unsigned short)(u >> 16);
}
__device__ __forceinline__ float b2f(unsigned short h) {
    union { uint32_t u; float f; } v; v.u = ((uint32_t)h) << 16;
    return v.f;
}

// ---------------- f32 -> bf16 convert ----------------
__global__ __launch_bounds__(256) void cvt_kernel(const float* __restrict__ in,
                                                  unsigned short* __restrict__ out,
                                                  int n) {
    int i = (blockIdx.x * 256 + threadIdx.x) * 4;
    if (i >= n) return;
    float4 v = *reinterpret_cast<const float4*>(in + i);
    ushort4 o;
    o.x = f2b(v.x); o.y = f2b(v.y); o.z = f2b(v.z); o.w = f2b(v.w);
    *reinterpret_cast<ushort4*>(out + i) = o;
}

#define GLD16(gp, lp) \
  __builtin_amdgcn_global_load_lds((const __attribute__((address_space(1))) void*)(gp), \
                                   (__attribute__((address_space(3))) void*)(lp), 16, 0, 0)

// ---------------- m97-structure bf16 GEMM: C = A @ B^T (+bias) ----------------
template<int OUT_BF16, int HAS_BIAS>
__global__ __launch_bounds__(256) void gemm_bt(const unsigned short* __restrict__ A,
                                               const unsigned short* __restrict__ Bm,
                                               const float* __restrict__ bias,
                                               void* __restrict__ C,
                                               int M, int N, int K) {
    __shared__ unsigned short As[128 * 32];
    __shared__ unsigned short Bs[128 * 32];
    const int tid = threadIdx.x;
    const int wave = tid >> 6, lane = tid & 63;
    const int lr = lane & 15, lg = lane >> 4;
    const int m0 = blockIdx.x * 128, n0 = blockIdx.y * 128;
    const int wr = wave >> 1, wc = wave & 1;

    const int srow = lane >> 2;
    const int skk  = (lane & 3) * 8;

    f32x4 acc[4][4] = {};

    for (int k0 = 0; k0 < K; k0 += 32) {
        __syncthreads();
        #pragma unroll
        for (int c = 0; c < 2; ++c) {
            int ch = c * 4 + wave;
            int row = ch * 16 + srow;
            GLD16(A  + (size_t)(m0 + row) * K + k0 + skk, As + ch * 512);
            GLD16(Bm + (size_t)(n0 + row) * K + k0 + skk, Bs + ch * 512);
        }
        __syncthreads();
        bf16x8 af[4], bf[4];
        #pragma unroll
        for (int i = 0; i < 4; ++i)
            af[i] = *reinterpret_cast<const bf16x8*>(As + (wr * 64 + i * 16 + lr) * 32 + lg * 8);
        #pragma unroll
        for (int j = 0; j < 4; ++j)
            bf[j] = *reinterpret_cast<const bf16x8*>(Bs + (wc * 64 + j * 16 + lr) * 32 + lg * 8);
        #pragma unroll
        for (int i = 0; i < 4; ++i)
            #pragma unroll
            for (int j = 0; j < 4; ++j)
                acc[i][j] = __builtin_amdgcn_mfma_f32_16x16x32_bf16(af[i], bf[j], acc[i][j], 0, 0, 0);
    }

    const int crow0 = m0 + wr * 64;
    const int ccol0 = n0 + wc * 64;
    #pragma unroll
    for (int j = 0; j < 4; ++j) {
        int col = ccol0 + j * 16 + lr;
        float bv = 0.f;
        if (HAS_BIAS) bv = bias[col];
        #pragma unroll
        for (int i = 0; i < 4; ++i) {
            #pragma unroll
            for (int r = 0; r < 4; ++r) {
                int row = crow0 + i * 16 + lg * 4 + r;
                float vv = acc[i][j][r] + bv;
                if (OUT_BF16)
                    reinterpret_cast<unsigned short*>(C)[(size_t)row * N + col] = f2b(vv);
                else
                    reinterpret_cast<float*>(C)[(size_t)row * N + col] = vv;
            }
        }
    }
}

// ---------------- 256x256 8-phase bf16 GEMM: C = A @ B^T (+bias), bf16 or f32 out ----------------
// R9-proven body (146 us @ 4096^3, MfmaUtil 40%, 0 bank conflicts) + XCD-region swizzle
// (FETCH 170->98 MB, timing-neutral but lowers HBM pressure; kept).
template<int OUT_BF16, int HAS_BIAS>
__global__ __launch_bounds__(512, 2) void gemm8p(const unsigned short* __restrict__ A,
                                                 const unsigned short* __restrict__ Bm,
                                                 const float* __restrict__ bias,
                                                 void* __restrict__ Cv,
                                                 int M, int N, int K, int ldc) {
    __shared__ unsigned short As[2][16384];   // [buf][256r][64c] bf16, swizzled contents
    __shared__ unsigned short Bs[2][16384];

    const int tid = threadIdx.x;
    const int w = tid >> 6, l = tid & 63;
    const int lr = l & 15, lg = l >> 4;
    const int wm = w >> 2, wn = w & 3;

    // XCD-region swizzle over a 16x16 tile grid (requires gridDim.x == 256)
    const int fid = blockIdx.x;
    const int xcd = fid & 7, t = fid >> 3;
    const int mt = (xcd >> 1) * 4 + (t >> 3);
    const int nt = (xcd & 1) * 8 + (t & 7);
    const int m0 = mt * 256, n0 = nt * 256;

    const int cb   = (l & 7) ^ (l >> 3);   // inverse-swizzled source colblock
    const int srow = w * 8 + (l >> 3);     // staging row within 64-row subblock
    const int axk  = lr & 7;               // read-side XOR key (row&7 == lr&7)

    f32x4 acc[8][4] = {};
    bf16x8 af[4][2], bfr[4][2];

    auto stageA = [&](int buf, int kt) {
        #pragma unroll
        for (int i = 0; i < 4; ++i)
            GLD16(A + (size_t)(m0 + i * 64 + srow) * K + kt * 64 + cb * 8,
                  &As[buf][i * 4096 + w * 512]);
    };
    auto stageB = [&](int buf, int kt) {
        #pragma unroll
        for (int i = 0; i < 4; ++i)
            GLD16(Bm + (size_t)(n0 + i * 64 + srow) * K + kt * 64 + cb * 8,
                  &Bs[buf][i * 4096 + w * 512]);
    };

    const int NT = K >> 6;

    stageA(0, 0);
    stageB(0, 0);
    asm volatile("s_waitcnt vmcnt(0)" ::: "memory");
    __builtin_amdgcn_s_barrier();

    const int arow = wm * 128 + lr;
    const int brow = wn * 64 + lr;

    #pragma unroll 1
    for (int t2 = 0; t2 < NT; ++t2) {
        const int buf = t2 & 1;
        const bool pre = (t2 + 1) < NT;

        // ---------- phase 0: A-half0 frags + B n0 frags; stage A' ----------
        #pragma unroll
        for (int f = 0; f < 4; ++f)
            #pragma unroll
            for (int ks = 0; ks < 2; ++ks)
                af[f][ks] = *reinterpret_cast<const bf16x8*>(
                    &As[buf][(arow + f * 16) * 64 + (((ks * 4 + lg) ^ axk) * 8)]);
        #pragma unroll
        for (int nf = 0; nf < 2; ++nf)
            #pragma unroll
            for (int ks = 0; ks < 2; ++ks)
                bfr[nf][ks] = *reinterpret_cast<const bf16x8*>(
                    &Bs[buf][(brow + nf * 16) * 64 + (((ks * 4 + lg) ^ axk) * 8)]);
        if (pre) stageA(buf ^ 1, t2 + 1);
        asm volatile("" ::: "memory");
        __builtin_amdgcn_s_barrier();
        asm volatile("s_waitcnt lgkmcnt(0)" ::: "memory");
        __builtin_amdgcn_sched_barrier(0);
        __builtin_amdgcn_s_setprio(1);
        #pragma unroll
        for (int f = 0; f < 4; ++f)
            #pragma unroll
            for (int nf = 0; nf < 2; ++nf)
                #pragma unroll
                for (int ks = 0; ks < 2; ++ks)
                    acc[f][nf] = __builtin_amdgcn_mfma_f32_16x16x32_bf16(af[f][ks], bfr[nf][ks], acc[f][nf], 0, 0, 0);
        __builtin_amdgcn_s_setprio(0);
        __builtin_amdgcn_s_barrier();

        // ---------- phase 1: B n1 frags; stage B' ----------
        #pragma unroll
        for (int nf = 2; nf < 4; ++nf)
            #pragma unroll
            for (int ks = 0; ks < 2; ++ks)
                bfr[nf][ks] = *reinterpret_cast<const bf16x8*>(
                    &Bs[buf][(brow + nf * 16) * 64 + (((ks * 4 + lg) ^ axk) * 8)]);
        if (pre) stageB(buf ^ 1, t2 + 1);
        asm volatile("" ::: "memory");
        __builtin_amdgcn_s_barrier();
        asm volatile("s_waitcnt lgkmcnt(0)" ::: "memory");
        __builtin_amdgcn_sched_barrier(0);
        __builtin_amdgcn_s_setprio(1);
        #pragma unroll
        for (int f = 0; f < 4; ++f)
            #pragma unroll
            for (int nf = 2; nf < 4; ++nf)
                #pragma unroll
                for (int ks = 0; ks < 2; ++ks)
                    acc[f][nf] = __builtin_amdgcn_mfma_f32_16x16x32_bf16(af[f][ks], bfr[nf][ks], acc[f][nf], 0, 0, 0);
        __builtin_amdgcn_s_setprio(0);
        __builtin_amdgcn_s_barrier();

        // ---------- phase 2: A-half1 frags (overwrite af) ----------
        #pragma unroll
        for (int f = 0; f < 4; ++f)
            #pragma unroll
            for (int ks = 0; ks < 2; ++ks)
                af[f][ks] = *reinterpret_cast<const bf16x8*>(
                    &As[buf][(arow + 64 + f * 16) * 64 + (((ks * 4 + lg) ^ axk) * 8)]);
        asm volatile("" ::: "memory");
        __builtin_amdgcn_s_barrier();
        asm volatile("s_waitcnt lgkmcnt(0)" ::: "memory");
        __builtin_amdgcn_sched_barrier(0);
        __builtin_amdgcn_s_setprio(1);
        #pragma unroll
        for (int f = 0; f < 4; ++f)
            #pragma unroll
            for (int nf = 2; nf < 4; ++nf)
                #pragma unroll
                for (int ks = 0; ks < 2; ++ks)
                    acc[4 + f][nf] = __builtin_amdgcn_mfma_f32_16x16x32_bf16(af[f][ks], bfr[nf][ks], acc[4 + f][nf], 0, 0, 0);
        __builtin_amdgcn_s_setprio(0);
        __builtin_amdgcn_s_barrier();

        // ---------- phase 3: no reads; MFMA m-half1 x n0; tile boundary ----------
        __builtin_amdgcn_s_setprio(1);
        #pragma unroll
        for (int f = 0; f < 4; ++f)
            #pragma unroll
            for (int nf = 0; nf < 2; ++nf)
                #pragma unroll
                for (int ks = 0; ks < 2; ++ks)
                    acc[4 + f][nf] = __builtin_amdgcn_mfma_f32_16x16x32_bf16(af[f][ks], bfr[nf][ks], acc[4 + f][nf], 0, 0, 0);
        __builtin_amdgcn_s_setprio(0);
        asm volatile("s_waitcnt vmcnt(0)" ::: "memory");   // staged loads issued >=2 phases ago
        __builtin_amdgcn_s_barrier();
    }

    // epilogue
    #pragma unroll
    for (int nf = 0; nf < 4; ++nf) {
        const int col = n0 + wn * 64 + nf * 16 + lr;
        float bv = 0.f;
        if (HAS_BIAS) bv = bias[col];
        #pragma unroll
        for (int f = 0; f < 8; ++f)
            #pragma unroll
            for (int rr = 0; rr < 4; ++rr) {
                const size_t row = m0 + wm * 128 + f * 16 + lg * 4 + rr;
                float vv = acc[f][nf][rr] + bv;
                if (OUT_BF16)
                    reinterpret_cast<unsigned short*>(Cv)[row * ldc + col] = f2b(vv);
                else
                    reinterpret_cast<float*>(Cv)[row * ldc + col] = vv;
            }
    }
}

// ---------------- RoPE + GQA scatter (q pre-scaled by log2e/sqrt(128)) ----------------
__global__ __launch_bounds__(256) void rope_scatter(const unsigned short* __restrict__ mixed,
                                                    const float* __restrict__ cache,
                                                    unsigned short* __restrict__ q,
                                                    unsigned short* __restrict__ k,
                                                    unsigned short* __restrict__ v) {
    int idx = blockIdx.x * 256 + threadIdx.x;
    int c = idx & 15;
    int t = idx >> 4;
    int head = t % 36;
    int bs = t / 36;
    int s = bs & 2047;
    int batch = bs >> 11;

    const unsigned short* src = mixed + (size_t)bs * QKVO + head * 128 + c * 8;
    bf16x8 xv = *reinterpret_cast<const bf16x8*>(src);
    float x[8];
    #pragma unroll
    for (int j = 0; j < 8; ++j) x[j] = b2f((unsigned short)xv[j]);

    if (head < 34 && c < 8) {   // rope on first 64 dims, interleaved pairs
        const float* cp = cache + ((size_t)s * 32 + c * 4) * 2;
        #pragma unroll
        for (int jj = 0; jj < 4; ++jj) {
            float co = cp[jj * 2 + 0], si = cp[jj * 2 + 1];
            float x0 = x[2 * jj], x1 = x[2 * jj + 1];
            x[2 * jj]     = x0 * co - x1 * si;
            x[2 * jj + 1] = x1 * co + x0 * si;
        }
    }
    if (head < 32) {            // fold softmax scale*log2e into q
        #pragma unroll
        for (int j = 0; j < 8; ++j) x[j] *= 0.12751743f;   // log2e/sqrt(128)
    }
    bf16x8 ov;
    #pragma unroll
    for (int j = 0; j < 8; ++j) ov[j] = (short)f2b(x[j]);

    unsigned short* dst;
    if (head < 32)
        dst = q + (((size_t)(batch * NH_ + head) * SQ_ + s) * HN_) + c * 8;
    else if (head < 34)
        dst = k + (((size_t)(batch * NG_ + (head - 32)) * SQ_ + s) * HN_) + c * 8;
    else
        dst = v + (((size_t)(batch * NG_ + (head - 34)) * SQ_ + s) * HN_) + c * 8;
    *reinterpret_cast<bf16x8*>(dst) = ov;
}

// ---------------- V transpose: [bg][s][d] -> [bg][d][s] (XOR-swizzled LDS) ----------------
__global__ __launch_bounds__(256) void vtrans_kernel(const unsigned short* __restrict__ v,
                                                     unsigned short* __restrict__ vt) {
    __shared__ __align__(16) unsigned short T[64 * 128];
    const int bg = blockIdx.x >> 5;
    const int st = blockIdx.x & 31;
    const int s0 = st * 64;
    const int tid = threadIdx.x;
    const unsigned short* src = v + (size_t)bg * SQ_ * HN_;
    unsigned short* dst = vt + (size_t)bg * SQ_ * HN_;
    char* Tb = (char*)T;
    #pragma unroll
    for (int it = 0; it < 4; ++it) {
        int idx = it * 256 + tid;
        int r = idx >> 4, c = idx & 15;
        bf16x8 x = *reinterpret_cast<const bf16x8*>(src + (size_t)(s0 + r) * HN_ + c * 8);
        int byt = (r * 256 + c * 16) ^ (((r >> 3) & 7) << 4);
        *reinterpret_cast<bf16x8*>(Tb + byt) = x;
    }
    __syncthreads();
    #pragma unroll
    for (int it = 0; it < 4; ++it) {
        int idx = it * 256 + tid;
        int d = idx >> 3, sc = idx & 7;
        bf16x8 o;
        #pragma unroll
        for (int j = 0; j < 8; ++j) {
            int s = sc * 8 + j;
            int byt = (s * 256 + d * 2) ^ (((s >> 3) & 7) << 4);
            o[j] = *reinterpret_cast<const unsigned short*>(Tb + byt);
        }
        *reinterpret_cast<bf16x8*>(dst + (size_t)d * SQ_ + s0 + sc * 8) = o;
    }
}

// ---------------- causal GQA flash attention ----------------
// 8 waves; K AND V block-staged in LDS (dbuf, both-sides XOR swizzle); one vmcnt(0)+barrier
// per tile, next-tile stage issued at loop top. launch_bounds MUST stay (512,2) —
// (512,4) caps VGPR at 64 and spills acc to scratch (R11, 8x regression).
// qt mapping pairs heavy+light blocks on the same CU: blocks n and n+256 share a CU
// (XCD=n%8, slot=(n/8)%32); y<4 -> qt=7-y (dispatched first), y>=4 -> qt=y-4.
// Per-CU tile totals: (7,0),(6,1),(5,2),(4,3) = 36 each (was 48/40/32/24 with qt=7-y).
__global__ __launch_bounds__(512, 2) void attn_kernel(const unsigned short* __restrict__ Q,
                                                      const unsigned short* __restrict__ K,
                                                      const unsigned short* __restrict__ VT,
                                                      unsigned short* __restrict__ ctx) {
    __shared__ __align__(16) unsigned short Ks[2][8192];   // [buf][key 64][d 128] swizzled
    __shared__ __align__(16) unsigned short Vs[2][8192];   // [buf][d 128][key 64] swizzled
    __shared__ __align__(16) unsigned short Pl[8][32][72]; // per-wave P round-trip

    const int bh = blockIdx.x;
    const int y = (int)blockIdx.y;
    const int qt = (y < 4) ? (7 - y) : (y - 4);   // heavy first, paired with light on-CU
    const int batch = bh >> 5, h = bh & 31, g = h >> 4;
    const int tid = threadIdx.x, wave = tid >> 6, lane = tid & 63;
    const int lr = lane & 15, lg = lane >> 4;
    const int q0w = qt * 256 + wave * 32;

    const unsigned short* Qp = Q + ((size_t)(batch * NH_ + h) * SQ_ + q0w) * HN_;
    const unsigned short* Kp = K + (size_t)(batch * NG_ + g) * SQ_ * HN_;
    const unsigned short* Vp = VT + (size_t)(batch * NG_ + g) * SQ_ * HN_;

    const int krow0 = lane >> 4;        // K: row = seg*4 + krow0, chunk(16B of d) = lane&15
    const int kcd   = lane & 15;
    const int vrow0 = lane >> 3;        // V: row = seg*8 + vrow0, chunk(16B of key) = lane&7
    const int vcd   = lane & 7;

    bf16x8 qf[2][4];
    #pragma unroll
    for (int mi = 0; mi < 2; ++mi)
        #pragma unroll
        for (int kd = 0; kd < 4; ++kd)
            qf[mi][kd] = *reinterpret_cast<const bf16x8*>(Qp + (size_t)(mi * 16 + lr) * HN_ + kd * 32 + lg * 8);

    f32x4 ctxa[2][8] = {};
    float mrow[2][4], lsump[2][4];
    #pragma unroll
    for (int mi = 0; mi < 2; ++mi)
        #pragma unroll
        for (int r = 0; r < 4; ++r) { mrow[mi][r] = -1e30f; lsump[mi][r] = 0.f; }

    const int nkt  = 4 * qt + 4;            // block-uniform tile count (covers wave 7)
    const int mykt = (q0w + 95) >> 6;       // this wave's active tiles

    {
        const int kb = 0;
        #pragma unroll
        for (int i = 0; i < 2; ++i) {
            int seg = wave * 2 + i;
            int krow = seg * 4 + krow0;
            int kcs = kcd ^ (krow & 7);
            GLD16(Kp + (size_t)(kb + krow) * HN_ + kcs * 8, &Ks[0][seg * 512]);
            int vrow = seg * 8 + vrow0;
            int vcs = vcd ^ (vrow & 7);
            GLD16(Vp + (size_t)vrow * SQ_ + kb + vcs * 8, &Vs[0][seg * 512]);
        }
    }
    asm volatile("s_waitcnt vmcnt(0)" ::: "memory");
    __builtin_amdgcn_s_barrier();

    #pragma unroll 1
    for (int kt = 0; kt < nkt; ++kt) {
        const int kbase = kt * 64;
        const int buf = kt & 1;

        if (kt + 1 < nkt) {
            const int kb = kbase + 64;
            #pragma unroll
            for (int i = 0; i < 2; ++i) {
                int seg = wave * 2 + i;
                int krow = seg * 4 + krow0;
                int kcs = kcd ^ (krow & 7);
                GLD16(Kp + (size_t)(kb + krow) * HN_ + kcs * 8, &Ks[buf ^ 1][seg * 512]);
                int vrow = seg * 8 + vrow0;
                int vcs = vcd ^ (vrow & 7);
                GLD16(Vp + (size_t)vrow * SQ_ + kb + vcs * 8, &Vs[buf ^ 1][seg * 512]);
            }
        }

        if (kt < mykt) {
            bf16x8 kfr[4][4];
            #pragma unroll
            for (int kf = 0; kf < 4; ++kf)
                #pragma unroll
                for (int kd = 0; kd < 4; ++kd)
                    kfr[kf][kd] = *reinterpret_cast<const bf16x8*>(
                        &Ks[buf][(kf * 16 + lr) * 128 + (((kd * 4 + lg) ^ (lr & 7)) * 8)]);

            f32x4 s[2][4] = {};
            __builtin_amdgcn_s_setprio(1);
            #pragma unroll
            for (int kf = 0; kf < 4; ++kf)
                #pragma unroll
                for (int kd = 0; kd < 4; ++kd)
                    #pragma unroll
                    for (int mi = 0; mi < 2; ++mi)
                        s[mi][kf] = __builtin_amdgcn_mfma_f32_16x16x32_bf16(qf[mi][kd], kfr[kf][kd], s[mi][kf], 0, 0, 0);
            __builtin_amdgcn_s_setprio(0);

            bf16x8 vfr[2][8];
            #pragma unroll
            for (int ks = 0; ks < 2; ++ks)
                #pragma unroll
                for (int df = 0; df < 8; ++df)
                    vfr[ks][df] = *reinterpret_cast<const bf16x8*>(
                        &Vs[buf][(df * 16 + lr) * 64 + (((ks * 4 + lg) ^ (lr & 7)) * 8)]);

            const bool maskTile = (kbase + 63 > q0w);   // wave-uniform
            if (maskTile) {
                #pragma unroll
                for (int mi = 0; mi < 2; ++mi)
                    #pragma unroll
                    for (int kf = 0; kf < 4; ++kf)
                        #pragma unroll
                        for (int r = 0; r < 4; ++r) {
                            int qrow = q0w + mi * 16 + lg * 4 + r;
                            int kcol = kbase + kf * 16 + lr;
                            if (kcol > qrow) s[mi][kf][r] = -1e30f;
                        }
            }

            float pmaxl[2][4];
            float worst = -1e30f;
            #pragma unroll
            for (int mi = 0; mi < 2; ++mi)
                #pragma unroll
                for (int r = 0; r < 4; ++r) {
                    float pm = fmaxf(fmaxf(s[mi][0][r], s[mi][1][r]), fmaxf(s[mi][2][r], s[mi][3][r]));
                    pmaxl[mi][r] = pm;
                    worst = fmaxf(worst, pm - mrow[mi][r]);
                }
            if (maskTile || __any(worst > 8.0f)) {
                #pragma unroll
                for (int mi = 0; mi < 2; ++mi)
                    #pragma unroll
                    for (int r = 0; r < 4; ++r) {
                        float pm = pmaxl[mi][r];
                        pm = fmaxf(pm, __shfl_xor(pm, 1));
                        pm = fmaxf(pm, __shfl_xor(pm, 2));
                        pm = fmaxf(pm, __shfl_xor(pm, 4));
                        pm = fmaxf(pm, __shfl_xor(pm, 8));
                        float mnew = fmaxf(mrow[mi][r], pm);
                        float resc = exp2f(mrow[mi][r] - mnew);
                        mrow[mi][r] = mnew;
                        lsump[mi][r] *= resc;
                        #pragma unroll
                        for (int df = 0; df < 8; ++df)
                            ctxa[mi][df][r] *= resc;
                    }
            }

            #pragma unroll
            for (int mi = 0; mi < 2; ++mi)
                #pragma unroll
                for (int r = 0; r < 4; ++r) {
                    float m = mrow[mi][r];
                    #pragma unroll
                    for (int kf = 0; kf < 4; ++kf) {
                        float p = exp2f(s[mi][kf][r] - m);
                        lsump[mi][r] += p;
                        Pl[wave][mi * 16 + lg * 4 + r][kf * 16 + lr] = f2b(p);
                    }
                }
            asm volatile("s_waitcnt lgkmcnt(0)" ::: "memory");
            __builtin_amdgcn_sched_barrier(0);

            bf16x8 pf[2][2];
            #pragma unroll
            for (int ks = 0; ks < 2; ++ks)
                #pragma unroll
                for (int mi = 0; mi < 2; ++mi)
                    pf[ks][mi] = *reinterpret_cast<const bf16x8*>(&Pl[wave][mi * 16 + lr][ks * 32 + lg * 8]);

            __builtin_amdgcn_s_setprio(1);
            #pragma unroll
            for (int ks = 0; ks < 2; ++ks)
                #pragma unroll
                for (int df = 0; df < 8; ++df)
                    #pragma unroll
                    for (int mi = 0; mi < 2; ++mi)
                        ctxa[mi][df] = __builtin_amdgcn_mfma_f32_16x16x32_bf16(pf[ks][mi], vfr[ks][df], ctxa[mi][df], 0, 0, 0);
            __builtin_amdgcn_s_setprio(0);
        }

        asm volatile("s_waitcnt vmcnt(0)" ::: "memory");   // next-tile staging complete
        __builtin_amdgcn_s_barrier();
    }

    #pragma unroll
    for (int mi = 0; mi < 2; ++mi) {
        #pragma unroll
        for (int r = 0; r < 4; ++r) {
            float ls = lsump[mi][r];
            ls += __shfl_xor(ls, 1);
            ls += __shfl_xor(ls, 2);
            ls += __shfl_xor(ls, 4);
            ls += __shfl_xor(ls, 8);
            float inv = 1.f / ls;
            int row = batch * SQ_ + q0w + mi * 16 + lg * 4 + r;
            #pragma unroll
            for (int df = 0; df < 8; ++df) {
                int col = h * HN_ + df * 16 + lr;
                ctx[(size_t)row * (NH_ * HN_) + col] = f2b(ctxa[mi][df][r] * inv);
            }
        }
    }
}

extern "C" void kernel_launch(void* const* d_in, const int* in_sizes, int n_in,
                              void* d_out, int out_size, void* d_ws, size_t ws_size,
                              hipStream_t stream) {
    const float* hs      = (const float*)d_in[0];
    const float* cache   = (const float*)d_in[1];
    const float* w_qkv   = (const float*)d_in[2];
    const float* b_qkv   = (const float*)d_in[3];
    const float* w_dense = (const float*)d_in[4];
    float* out = (float*)d_out;

    char* p = (char*)d_ws;
    unsigned short* hs_b    = (unsigned short*)p; p += (size_t)16777216 * 2;  // [4096][4096]
    unsigned short* wqkv_b  = (unsigned short*)p; p += (size_t)18874368 * 2;  // [4608][4096]
    unsigned short* wd_b    = (unsigned short*)p; p += (size_t)16777216 * 2;  // [4096][4096]
    unsigned short* mixed_b = (unsigned short*)p; p += (size_t)18874368 * 2;  // [4096][4608]
    unsigned short* q_b     = (unsigned short*)p; p += (size_t)16777216 * 2;  // [2][32][2048][128]
    unsigned short* k_b     = (unsigned short*)p; p += (size_t)1048576 * 2;   // [2][2][2048][128]
    unsigned short* v_b     = (unsigned short*)p; p += (size_t)1048576 * 2;   // [2][2][2048][128]
    unsigned short* vt_b    = (unsigned short*)p; p += (size_t)1048576 * 2;   // [2][2][128][2048]
    unsigned short* ctx_b   = (unsigned short*)p; p += (size_t)16777216 * 2;  // [4096][4096]

    cvt_kernel<<<16384, 256, 0, stream>>>(hs, hs_b, 16777216);
    cvt_kernel<<<18432, 256, 0, stream>>>(w_qkv, wqkv_b, 18874368);
    cvt_kernel<<<16384, 256, 0, stream>>>(w_dense, wd_b, 16777216);

    // QKV = hs @ w_qkv^T + b: Q cols (4096) via 8-phase 256-block launch; K/V cols (512) via m97
    gemm8p<1, 1><<<256, 512, 0, stream>>>(hs_b, wqkv_b, b_qkv, (void*)mixed_b,
                                          4096, 4096, 4096, QKVO);
    dim3 gr(32, 4);
    gemm_bt<1, 1><<<gr, 256, 0, stream>>>(hs_b, wqkv_b + (size_t)4096 * 4096, b_qkv + 4096,
                                          (void*)(mixed_b + 4096), 4096, QKVO, 4096);

    rope_scatter<<<9216, 256, 0, stream>>>(mixed_b, cache, q_b, k_b, v_b);
    vtrans_kernel<<<128, 256, 0, stream>>>(v_b, vt_b);

    dim3 g2(64, 8);
    attn_kernel<<<g2, 512, 0, stream>>>(q_b, k_b, vt_b, ctx_b);

    gemm8p<0, 0><<<256, 512, 0, stream>>>(ctx_b, wd_b, nullptr, out, 4096, 4096, 4096, 4096);
}

// Round 16
// 535.933 us; speedup vs baseline: 1.0360x; 1.0360x over previous
//
#include <hip/hip_runtime.h>
#include <hip/hip_bf16.h>
#include <stdint.h>

typedef __attribute__((ext_vector_type(8))) short bf16x8;
typedef __attribute__((ext_vector_type(4))) float f32x4;

#define B_   2
#define SQ_  2048
#define H_   4096
#define NH_  32
#define NG_  2
#define HN_  128
#define QKVO 4608

__device__ __forceinline__ unsigned short f2b(float f) {
    union { float f; uint32_t u; } v; v.f = f;
    uint32_t u = v.u;
    u += 0x7FFFu + ((u >> 16) & 1u);   // round-to-nearest-even
    return (unsigned short)(u >> 16);
}
__device__ __forceinline__ float b2f(unsigned short h) {
    union { uint32_t u; float f; } v; v.u = ((uint32_t)h) << 16;
    return v.f;
}

// ---------------- f32 -> bf16 convert ----------------
__global__ __launch_bounds__(256) void cvt_kernel(const float* __restrict__ in,
                                                  unsigned short* __restrict__ out,
                                                  int n) {
    int i = (blockIdx.x * 256 + threadIdx.x) * 4;
    if (i >= n) return;
    float4 v = *reinterpret_cast<const float4*>(in + i);
    ushort4 o;
    o.x = f2b(v.x); o.y = f2b(v.y); o.z = f2b(v.z); o.w = f2b(v.w);
    *reinterpret_cast<ushort4*>(out + i) = o;
}

#define GLD16(gp, lp) \
  __builtin_amdgcn_global_load_lds((const __attribute__((address_space(1))) void*)(gp), \
                                   (__attribute__((address_space(3))) void*)(lp), 16, 0, 0)

// ---------------- m97-structure bf16 GEMM: C = A @ B^T (+bias) ----------------
template<int OUT_BF16, int HAS_BIAS>
__global__ __launch_bounds__(256) void gemm_bt(const unsigned short* __restrict__ A,
                                               const unsigned short* __restrict__ Bm,
                                               const float* __restrict__ bias,
                                               void* __restrict__ C,
                                               int M, int N, int K) {
    __shared__ unsigned short As[128 * 32];
    __shared__ unsigned short Bs[128 * 32];
    const int tid = threadIdx.x;
    const int wave = tid >> 6, lane = tid & 63;
    const int lr = lane & 15, lg = lane >> 4;
    const int m0 = blockIdx.x * 128, n0 = blockIdx.y * 128;
    const int wr = wave >> 1, wc = wave & 1;

    const int srow = lane >> 2;
    const int skk  = (lane & 3) * 8;

    f32x4 acc[4][4] = {};

    for (int k0 = 0; k0 < K; k0 += 32) {
        __syncthreads();
        #pragma unroll
        for (int c = 0; c < 2; ++c) {
            int ch = c * 4 + wave;
            int row = ch * 16 + srow;
            GLD16(A  + (size_t)(m0 + row) * K + k0 + skk, As + ch * 512);
            GLD16(Bm + (size_t)(n0 + row) * K + k0 + skk, Bs + ch * 512);
        }
        __syncthreads();
        bf16x8 af[4], bf[4];
        #pragma unroll
        for (int i = 0; i < 4; ++i)
            af[i] = *reinterpret_cast<const bf16x8*>(As + (wr * 64 + i * 16 + lr) * 32 + lg * 8);
        #pragma unroll
        for (int j = 0; j < 4; ++j)
            bf[j] = *reinterpret_cast<const bf16x8*>(Bs + (wc * 64 + j * 16 + lr) * 32 + lg * 8);
        #pragma unroll
        for (int i = 0; i < 4; ++i)
            #pragma unroll
            for (int j = 0; j < 4; ++j)
                acc[i][j] = __builtin_amdgcn_mfma_f32_16x16x32_bf16(af[i], bf[j], acc[i][j], 0, 0, 0);
    }

    const int crow0 = m0 + wr * 64;
    const int ccol0 = n0 + wc * 64;
    #pragma unroll
    for (int j = 0; j < 4; ++j) {
        int col = ccol0 + j * 16 + lr;
        float bv = 0.f;
        if (HAS_BIAS) bv = bias[col];
        #pragma unroll
        for (int i = 0; i < 4; ++i) {
            #pragma unroll
            for (int r = 0; r < 4; ++r) {
                int row = crow0 + i * 16 + lg * 4 + r;
                float vv = acc[i][j][r] + bv;
                if (OUT_BF16)
                    reinterpret_cast<unsigned short*>(C)[(size_t)row * N + col] = f2b(vv);
                else
                    reinterpret_cast<float*>(C)[(size_t)row * N + col] = vv;
            }
        }
    }
}

// ---------------- 256x256 8-phase bf16 GEMM: C = A @ B^T (+bias), bf16 or f32 out ----------------
// R9-proven body (146 us @ 4096^3, MfmaUtil 40%, 0 bank conflicts) + XCD-region swizzle
// (FETCH 170->98 MB, timing-neutral but lowers HBM pressure; kept).
template<int OUT_BF16, int HAS_BIAS>
__global__ __launch_bounds__(512, 2) void gemm8p(const unsigned short* __restrict__ A,
                                                 const unsigned short* __restrict__ Bm,
                                                 const float* __restrict__ bias,
                                                 void* __restrict__ Cv,
                                                 int M, int N, int K, int ldc) {
    __shared__ unsigned short As[2][16384];   // [buf][256r][64c] bf16, swizzled contents
    __shared__ unsigned short Bs[2][16384];

    const int tid = threadIdx.x;
    const int w = tid >> 6, l = tid & 63;
    const int lr = l & 15, lg = l >> 4;
    const int wm = w >> 2, wn = w & 3;

    // XCD-region swizzle over a 16x16 tile grid (requires gridDim.x == 256)
    const int fid = blockIdx.x;
    const int xcd = fid & 7, t = fid >> 3;
    const int mt = (xcd >> 1) * 4 + (t >> 3);
    const int nt = (xcd & 1) * 8 + (t & 7);
    const int m0 = mt * 256, n0 = nt * 256;

    const int cb   = (l & 7) ^ (l >> 3);   // inverse-swizzled source colblock
    const int srow = w * 8 + (l >> 3);     // staging row within 64-row subblock
    const int axk  = lr & 7;               // read-side XOR key (row&7 == lr&7)

    f32x4 acc[8][4] = {};
    bf16x8 af[4][2], bfr[4][2];

    auto stageA = [&](int buf, int kt) {
        #pragma unroll
        for (int i = 0; i < 4; ++i)
            GLD16(A + (size_t)(m0 + i * 64 + srow) * K + kt * 64 + cb * 8,
                  &As[buf][i * 4096 + w * 512]);
    };
    auto stageB = [&](int buf, int kt) {
        #pragma unroll
        for (int i = 0; i < 4; ++i)
            GLD16(Bm + (size_t)(n0 + i * 64 + srow) * K + kt * 64 + cb * 8,
                  &Bs[buf][i * 4096 + w * 512]);
    };

    const int NT = K >> 6;

    stageA(0, 0);
    stageB(0, 0);
    asm volatile("s_waitcnt vmcnt(0)" ::: "memory");
    __builtin_amdgcn_s_barrier();

    const int arow = wm * 128 + lr;
    const int brow = wn * 64 + lr;

    #pragma unroll 1
    for (int t2 = 0; t2 < NT; ++t2) {
        const int buf = t2 & 1;
        const bool pre = (t2 + 1) < NT;

        // ---------- phase 0: A-half0 frags + B n0 frags; stage A' ----------
        #pragma unroll
        for (int f = 0; f < 4; ++f)
            #pragma unroll
            for (int ks = 0; ks < 2; ++ks)
                af[f][ks] = *reinterpret_cast<const bf16x8*>(
                    &As[buf][(arow + f * 16) * 64 + (((ks * 4 + lg) ^ axk) * 8)]);
        #pragma unroll
        for (int nf = 0; nf < 2; ++nf)
            #pragma unroll
            for (int ks = 0; ks < 2; ++ks)
                bfr[nf][ks] = *reinterpret_cast<const bf16x8*>(
                    &Bs[buf][(brow + nf * 16) * 64 + (((ks * 4 + lg) ^ axk) * 8)]);
        if (pre) stageA(buf ^ 1, t2 + 1);
        asm volatile("" ::: "memory");
        __builtin_amdgcn_s_barrier();
        asm volatile("s_waitcnt lgkmcnt(0)" ::: "memory");
        __builtin_amdgcn_sched_barrier(0);
        __builtin_amdgcn_s_setprio(1);
        #pragma unroll
        for (int f = 0; f < 4; ++f)
            #pragma unroll
            for (int nf = 0; nf < 2; ++nf)
                #pragma unroll
                for (int ks = 0; ks < 2; ++ks)
                    acc[f][nf] = __builtin_amdgcn_mfma_f32_16x16x32_bf16(af[f][ks], bfr[nf][ks], acc[f][nf], 0, 0, 0);
        __builtin_amdgcn_s_setprio(0);
        __builtin_amdgcn_s_barrier();

        // ---------- phase 1: B n1 frags; stage B' ----------
        #pragma unroll
        for (int nf = 2; nf < 4; ++nf)
            #pragma unroll
            for (int ks = 0; ks < 2; ++ks)
                bfr[nf][ks] = *reinterpret_cast<const bf16x8*>(
                    &Bs[buf][(brow + nf * 16) * 64 + (((ks * 4 + lg) ^ axk) * 8)]);
        if (pre) stageB(buf ^ 1, t2 + 1);
        asm volatile("" ::: "memory");
        __builtin_amdgcn_s_barrier();
        asm volatile("s_waitcnt lgkmcnt(0)" ::: "memory");
        __builtin_amdgcn_sched_barrier(0);
        __builtin_amdgcn_s_setprio(1);
        #pragma unroll
        for (int f = 0; f < 4; ++f)
            #pragma unroll
            for (int nf = 2; nf < 4; ++nf)
                #pragma unroll
                for (int ks = 0; ks < 2; ++ks)
                    acc[f][nf] = __builtin_amdgcn_mfma_f32_16x16x32_bf16(af[f][ks], bfr[nf][ks], acc[f][nf], 0, 0, 0);
        __builtin_amdgcn_s_setprio(0);
        __builtin_amdgcn_s_barrier();

        // ---------- phase 2: A-half1 frags (overwrite af) ----------
        #pragma unroll
        for (int f = 0; f < 4; ++f)
            #pragma unroll
            for (int ks = 0; ks < 2; ++ks)
                af[f][ks] = *reinterpret_cast<const bf16x8*>(
                    &As[buf][(arow + 64 + f * 16) * 64 + (((ks * 4 + lg) ^ axk) * 8)]);
        asm volatile("" ::: "memory");
        __builtin_amdgcn_s_barrier();
        asm volatile("s_waitcnt lgkmcnt(0)" ::: "memory");
        __builtin_amdgcn_sched_barrier(0);
        __builtin_amdgcn_s_setprio(1);
        #pragma unroll
        for (int f = 0; f < 4; ++f)
            #pragma unroll
            for (int nf = 2; nf < 4; ++nf)
                #pragma unroll
                for (int ks = 0; ks < 2; ++ks)
                    acc[4 + f][nf] = __builtin_amdgcn_mfma_f32_16x16x32_bf16(af[f][ks], bfr[nf][ks], acc[4 + f][nf], 0, 0, 0);
        __builtin_amdgcn_s_setprio(0);
        __builtin_amdgcn_s_barrier();

        // ---------- phase 3: no reads; MFMA m-half1 x n0; tile boundary ----------
        __builtin_amdgcn_s_setprio(1);
        #pragma unroll
        for (int f = 0; f < 4; ++f)
            #pragma unroll
            for (int nf = 0; nf < 2; ++nf)
                #pragma unroll
                for (int ks = 0; ks < 2; ++ks)
                    acc[4 + f][nf] = __builtin_amdgcn_mfma_f32_16x16x32_bf16(af[f][ks], bfr[nf][ks], acc[4 + f][nf], 0, 0, 0);
        __builtin_amdgcn_s_setprio(0);
        asm volatile("s_waitcnt vmcnt(0)" ::: "memory");   // staged loads issued >=2 phases ago
        __builtin_amdgcn_s_barrier();
    }

    // epilogue
    #pragma unroll
    for (int nf = 0; nf < 4; ++nf) {
        const int col = n0 + wn * 64 + nf * 16 + lr;
        float bv = 0.f;
        if (HAS_BIAS) bv = bias[col];
        #pragma unroll
        for (int f = 0; f < 8; ++f)
            #pragma unroll
            for (int rr = 0; rr < 4; ++rr) {
                const size_t row = m0 + wm * 128 + f * 16 + lg * 4 + rr;
                float vv = acc[f][nf][rr] + bv;
                if (OUT_BF16)
                    reinterpret_cast<unsigned short*>(Cv)[row * ldc + col] = f2b(vv);
                else
                    reinterpret_cast<float*>(Cv)[row * ldc + col] = vv;
            }
    }
}

// ---------------- RoPE + GQA scatter (q pre-scaled by log2e/sqrt(128)) ----------------
__global__ __launch_bounds__(256) void rope_scatter(const unsigned short* __restrict__ mixed,
                                                    const float* __restrict__ cache,
                                                    unsigned short* __restrict__ q,
                                                    unsigned short* __restrict__ k,
                                                    unsigned short* __restrict__ v) {
    int idx = blockIdx.x * 256 + threadIdx.x;
    int c = idx & 15;
    int t = idx >> 4;
    int head = t % 36;
    int bs = t / 36;
    int s = bs & 2047;
    int batch = bs >> 11;

    const unsigned short* src = mixed + (size_t)bs * QKVO + head * 128 + c * 8;
    bf16x8 xv = *reinterpret_cast<const bf16x8*>(src);
    float x[8];
    #pragma unroll
    for (int j = 0; j < 8; ++j) x[j] = b2f((unsigned short)xv[j]);

    if (head < 34 && c < 8) {   // rope on first 64 dims, interleaved pairs
        const float* cp = cache + ((size_t)s * 32 + c * 4) * 2;
        #pragma unroll
        for (int jj = 0; jj < 4; ++jj) {
            float co = cp[jj * 2 + 0], si = cp[jj * 2 + 1];
            float x0 = x[2 * jj], x1 = x[2 * jj + 1];
            x[2 * jj]     = x0 * co - x1 * si;
            x[2 * jj + 1] = x1 * co + x0 * si;
        }
    }
    if (head < 32) {            // fold softmax scale*log2e into q
        #pragma unroll
        for (int j = 0; j < 8; ++j) x[j] *= 0.12751743f;   // log2e/sqrt(128)
    }
    bf16x8 ov;
    #pragma unroll
    for (int j = 0; j < 8; ++j) ov[j] = (short)f2b(x[j]);

    unsigned short* dst;
    if (head < 32)
        dst = q + (((size_t)(batch * NH_ + head) * SQ_ + s) * HN_) + c * 8;
    else if (head < 34)
        dst = k + (((size_t)(batch * NG_ + (head - 32)) * SQ_ + s) * HN_) + c * 8;
    else
        dst = v + (((size_t)(batch * NG_ + (head - 34)) * SQ_ + s) * HN_) + c * 8;
    *reinterpret_cast<bf16x8*>(dst) = ov;
}

// ---------------- V transpose: [bg][s][d] -> [bg][d][s] (XOR-swizzled LDS) ----------------
__global__ __launch_bounds__(256) void vtrans_kernel(const unsigned short* __restrict__ v,
                                                     unsigned short* __restrict__ vt) {
    __shared__ __align__(16) unsigned short T[64 * 128];
    const int bg = blockIdx.x >> 5;
    const int st = blockIdx.x & 31;
    const int s0 = st * 64;
    const int tid = threadIdx.x;
    const unsigned short* src = v + (size_t)bg * SQ_ * HN_;
    unsigned short* dst = vt + (size_t)bg * SQ_ * HN_;
    char* Tb = (char*)T;
    #pragma unroll
    for (int it = 0; it < 4; ++it) {
        int idx = it * 256 + tid;
        int r = idx >> 4, c = idx & 15;
        bf16x8 x = *reinterpret_cast<const bf16x8*>(src + (size_t)(s0 + r) * HN_ + c * 8);
        int byt = (r * 256 + c * 16) ^ (((r >> 3) & 7) << 4);
        *reinterpret_cast<bf16x8*>(Tb + byt) = x;
    }
    __syncthreads();
    #pragma unroll
    for (int it = 0; it < 4; ++it) {
        int idx = it * 256 + tid;
        int d = idx >> 3, sc = idx & 7;
        bf16x8 o;
        #pragma unroll
        for (int j = 0; j < 8; ++j) {
            int s = sc * 8 + j;
            int byt = (s * 256 + d * 2) ^ (((s >> 3) & 7) << 4);
            o[j] = *reinterpret_cast<const unsigned short*>(Tb + byt);
        }
        *reinterpret_cast<bf16x8*>(dst + (size_t)d * SQ_ + s0 + sc * 8) = o;
    }
}

// ---------------- causal GQA flash attention (R14 config: best measured) ----------------
// 8 waves; K AND V block-staged in LDS (dbuf, both-sides XOR swizzle); one vmcnt(0)+barrier
// per tile, next-tile stage issued at loop top. launch_bounds MUST stay (512,2) —
// (512,4) caps VGPR at 64 and spills acc to scratch (R11, 8x regression).
// qt = 7 - blockIdx.y (LPT, heavy tiles dispatched first). The "balanced-pair" remap
// (R15) regressed 145->166 us — block->CU pairing model disproven; keep 7-y.
__global__ __launch_bounds__(512, 2) void attn_kernel(const unsigned short* __restrict__ Q,
                                                      const unsigned short* __restrict__ K,
                                                      const unsigned short* __restrict__ VT,
                                                      unsigned short* __restrict__ ctx) {
    __shared__ __align__(16) unsigned short Ks[2][8192];   // [buf][key 64][d 128] swizzled
    __shared__ __align__(16) unsigned short Vs[2][8192];   // [buf][d 128][key 64] swizzled
    __shared__ __align__(16) unsigned short Pl[8][32][72]; // per-wave P round-trip

    const int bh = blockIdx.x;
    const int qt = 7 - (int)blockIdx.y;       // LPT: heavy causal tiles first
    const int batch = bh >> 5, h = bh & 31, g = h >> 4;
    const int tid = threadIdx.x, wave = tid >> 6, lane = tid & 63;
    const int lr = lane & 15, lg = lane >> 4;
    const int q0w = qt * 256 + wave * 32;

    const unsigned short* Qp = Q + ((size_t)(batch * NH_ + h) * SQ_ + q0w) * HN_;
    const unsigned short* Kp = K + (size_t)(batch * NG_ + g) * SQ_ * HN_;
    const unsigned short* Vp = VT + (size_t)(batch * NG_ + g) * SQ_ * HN_;

    const int krow0 = lane >> 4;        // K: row = seg*4 + krow0, chunk(16B of d) = lane&15
    const int kcd   = lane & 15;
    const int vrow0 = lane >> 3;        // V: row = seg*8 + vrow0, chunk(16B of key) = lane&7
    const int vcd   = lane & 7;

    bf16x8 qf[2][4];
    #pragma unroll
    for (int mi = 0; mi < 2; ++mi)
        #pragma unroll
        for (int kd = 0; kd < 4; ++kd)
            qf[mi][kd] = *reinterpret_cast<const bf16x8*>(Qp + (size_t)(mi * 16 + lr) * HN_ + kd * 32 + lg * 8);

    f32x4 ctxa[2][8] = {};
    float mrow[2][4], lsump[2][4];
    #pragma unroll
    for (int mi = 0; mi < 2; ++mi)
        #pragma unroll
        for (int r = 0; r < 4; ++r) { mrow[mi][r] = -1e30f; lsump[mi][r] = 0.f; }

    const int nkt  = 4 * qt + 4;            // block-uniform tile count (covers wave 7)
    const int mykt = (q0w + 95) >> 6;       // this wave's active tiles

    {
        const int kb = 0;
        #pragma unroll
        for (int i = 0; i < 2; ++i) {
            int seg = wave * 2 + i;
            int krow = seg * 4 + krow0;
            int kcs = kcd ^ (krow & 7);
            GLD16(Kp + (size_t)(kb + krow) * HN_ + kcs * 8, &Ks[0][seg * 512]);
            int vrow = seg * 8 + vrow0;
            int vcs = vcd ^ (vrow & 7);
            GLD16(Vp + (size_t)vrow * SQ_ + kb + vcs * 8, &Vs[0][seg * 512]);
        }
    }
    asm volatile("s_waitcnt vmcnt(0)" ::: "memory");
    __builtin_amdgcn_s_barrier();

    #pragma unroll 1
    for (int kt = 0; kt < nkt; ++kt) {
        const int kbase = kt * 64;
        const int buf = kt & 1;

        if (kt + 1 < nkt) {
            const int kb = kbase + 64;
            #pragma unroll
            for (int i = 0; i < 2; ++i) {
                int seg = wave * 2 + i;
                int krow = seg * 4 + krow0;
                int kcs = kcd ^ (krow & 7);
                GLD16(Kp + (size_t)(kb + krow) * HN_ + kcs * 8, &Ks[buf ^ 1][seg * 512]);
                int vrow = seg * 8 + vrow0;
                int vcs = vcd ^ (vrow & 7);
                GLD16(Vp + (size_t)vrow * SQ_ + kb + vcs * 8, &Vs[buf ^ 1][seg * 512]);
            }
        }

        if (kt < mykt) {
            bf16x8 kfr[4][4];
            #pragma unroll
            for (int kf = 0; kf < 4; ++kf)
                #pragma unroll
                for (int kd = 0; kd < 4; ++kd)
                    kfr[kf][kd] = *reinterpret_cast<const bf16x8*>(
                        &Ks[buf][(kf * 16 + lr) * 128 + (((kd * 4 + lg) ^ (lr & 7)) * 8)]);

            f32x4 s[2][4] = {};
            __builtin_amdgcn_s_setprio(1);
            #pragma unroll
            for (int kf = 0; kf < 4; ++kf)
                #pragma unroll
                for (int kd = 0; kd < 4; ++kd)
                    #pragma unroll
                    for (int mi = 0; mi < 2; ++mi)
                        s[mi][kf] = __builtin_amdgcn_mfma_f32_16x16x32_bf16(qf[mi][kd], kfr[kf][kd], s[mi][kf], 0, 0, 0);
            __builtin_amdgcn_s_setprio(0);

            bf16x8 vfr[2][8];
            #pragma unroll
            for (int ks = 0; ks < 2; ++ks)
                #pragma unroll
                for (int df = 0; df < 8; ++df)
                    vfr[ks][df] = *reinterpret_cast<const bf16x8*>(
                        &Vs[buf][(df * 16 + lr) * 64 + (((ks * 4 + lg) ^ (lr & 7)) * 8)]);

            const bool maskTile = (kbase + 63 > q0w);   // wave-uniform
            if (maskTile) {
                #pragma unroll
                for (int mi = 0; mi < 2; ++mi)
                    #pragma unroll
                    for (int kf = 0; kf < 4; ++kf)
                        #pragma unroll
                        for (int r = 0; r < 4; ++r) {
                            int qrow = q0w + mi * 16 + lg * 4 + r;
                            int kcol = kbase + kf * 16 + lr;
                            if (kcol > qrow) s[mi][kf][r] = -1e30f;
                        }
            }

            float pmaxl[2][4];
            float worst = -1e30f;
            #pragma unroll
            for (int mi = 0; mi < 2; ++mi)
                #pragma unroll
                for (int r = 0; r < 4; ++r) {
                    float pm = fmaxf(fmaxf(s[mi][0][r], s[mi][1][r]), fmaxf(s[mi][2][r], s[mi][3][r]));
                    pmaxl[mi][r] = pm;
                    worst = fmaxf(worst, pm - mrow[mi][r]);
                }
            if (maskTile || __any(worst > 8.0f)) {
                #pragma unroll
                for (int mi = 0; mi < 2; ++mi)
                    #pragma unroll
                    for (int r = 0; r < 4; ++r) {
                        float pm = pmaxl[mi][r];
                        pm = fmaxf(pm, __shfl_xor(pm, 1));
                        pm = fmaxf(pm, __shfl_xor(pm, 2));
                        pm = fmaxf(pm, __shfl_xor(pm, 4));
                        pm = fmaxf(pm, __shfl_xor(pm, 8));
                        float mnew = fmaxf(mrow[mi][r], pm);
                        float resc = exp2f(mrow[mi][r] - mnew);
                        mrow[mi][r] = mnew;
                        lsump[mi][r] *= resc;
                        #pragma unroll
                        for (int df = 0; df < 8; ++df)
                            ctxa[mi][df][r] *= resc;
                    }
            }

            #pragma unroll
            for (int mi = 0; mi < 2; ++mi)
                #pragma unroll
                for (int r = 0; r < 4; ++r) {
                    float m = mrow[mi][r];
                    #pragma unroll
                    for (int kf = 0; kf < 4; ++kf) {
                        float p = exp2f(s[mi][kf][r] - m);
                        lsump[mi][r] += p;
                        Pl[wave][mi * 16 + lg * 4 + r][kf * 16 + lr] = f2b(p);
                    }
                }
            asm volatile("s_waitcnt lgkmcnt(0)" ::: "memory");
            __builtin_amdgcn_sched_barrier(0);

            bf16x8 pf[2][2];
            #pragma unroll
            for (int ks = 0; ks < 2; ++ks)
                #pragma unroll
                for (int mi = 0; mi < 2; ++mi)
                    pf[ks][mi] = *reinterpret_cast<const bf16x8*>(&Pl[wave][mi * 16 + lr][ks * 32 + lg * 8]);

            __builtin_amdgcn_s_setprio(1);
            #pragma unroll
            for (int ks = 0; ks < 2; ++ks)
                #pragma unroll
                for (int df = 0; df < 8; ++df)
                    #pragma unroll
                    for (int mi = 0; mi < 2; ++mi)
                        ctxa[mi][df] = __builtin_amdgcn_mfma_f32_16x16x32_bf16(pf[ks][mi], vfr[ks][df], ctxa[mi][df], 0, 0, 0);
            __builtin_amdgcn_s_setprio(0);
        }

        asm volatile("s_waitcnt vmcnt(0)" ::: "memory");   // next-tile staging complete
        __builtin_amdgcn_s_barrier();
    }

    #pragma unroll
    for (int mi = 0; mi < 2; ++mi) {
        #pragma unroll
        for (int r = 0; r < 4; ++r) {
            float ls = lsump[mi][r];
            ls += __shfl_xor(ls, 1);
            ls += __shfl_xor(ls, 2);
            ls += __shfl_xor(ls, 4);
            ls += __shfl_xor(ls, 8);
            float inv = 1.f / ls;
            int row = batch * SQ_ + q0w + mi * 16 + lg * 4 + r;
            #pragma unroll
            for (int df = 0; df < 8; ++df) {
                int col = h * HN_ + df * 16 + lr;
                ctx[(size_t)row * (NH_ * HN_) + col] = f2b(ctxa[mi][df][r] * inv);
            }
        }
    }
}

extern "C" void kernel_launch(void* const* d_in, const int* in_sizes, int n_in,
                              void* d_out, int out_size, void* d_ws, size_t ws_size,
                              hipStream_t stream) {
    const float* hs      = (const float*)d_in[0];
    const float* cache   = (const float*)d_in[1];
    const float* w_qkv   = (const float*)d_in[2];
    const float* b_qkv   = (const float*)d_in[3];
    const float* w_dense = (const float*)d_in[4];
    float* out = (float*)d_out;

    char* p = (char*)d_ws;
    unsigned short* hs_b    = (unsigned short*)p; p += (size_t)16777216 * 2;  // [4096][4096]
    unsigned short* wqkv_b  = (unsigned short*)p; p += (size_t)18874368 * 2;  // [4608][4096]
    unsigned short* wd_b    = (unsigned short*)p; p += (size_t)16777216 * 2;  // [4096][4096]
    unsigned short* mixed_b = (unsigned short*)p; p += (size_t)18874368 * 2;  // [4096][4608]
    unsigned short* q_b     = (unsigned short*)p; p += (size_t)16777216 * 2;  // [2][32][2048][128]
    unsigned short* k_b     = (unsigned short*)p; p += (size_t)1048576 * 2;   // [2][2][2048][128]
    unsigned short* v_b     = (unsigned short*)p; p += (size_t)1048576 * 2;   // [2][2][2048][128]
    unsigned short* vt_b    = (unsigned short*)p; p += (size_t)1048576 * 2;   // [2][2][128][2048]
    unsigned short* ctx_b   = (unsigned short*)p; p += (size_t)16777216 * 2;  // [4096][4096]

    cvt_kernel<<<16384, 256, 0, stream>>>(hs, hs_b, 16777216);
    cvt_kernel<<<18432, 256, 0, stream>>>(w_qkv, wqkv_b, 18874368);
    cvt_kernel<<<16384, 256, 0, stream>>>(w_dense, wd_b, 16777216);

    // QKV = hs @ w_qkv^T + b: Q cols (4096) via 8-phase 256-block launch; K/V cols (512) via m97
    gemm8p<1, 1><<<256, 512, 0, stream>>>(hs_b, wqkv_b, b_qkv, (void*)mixed_b,
                                          4096, 4096, 4096, QKVO);
    dim3 gr(32, 4);
    gemm_bt<1, 1><<<gr, 256, 0, stream>>>(hs_b, wqkv_b + (size_t)4096 * 4096, b_qkv + 4096,
                                          (void*)(mixed_b + 4096), 4096, QKVO, 4096);

    rope_scatter<<<9216, 256, 0, stream>>>(mixed_b, cache, q_b, k_b, v_b);
    vtrans_kernel<<<128, 256, 0, stream>>>(v_b, vt_b);

    dim3 g2(64, 8);
    attn_kernel<<<g2, 512, 0, stream>>>(q_b, k_b, vt_b, ctx_b);

    gemm8p<0, 0><<<256, 512, 0, stream>>>(ctx_b, wd_b, nullptr, out, 4096, 4096, 4096, 4096);
}